// Round 4
// baseline (614.015 us; speedup 1.0000x reference)
//
#include <hip/hip_runtime.h>
#include <hip/hip_bf16.h>

// B=4, M=3, N=2048, DIM=512, H=4, HD=128, SCALE=sqrt(128). BM=12.
// ws (bf16): Q [BM][H][N][HD] | K [BM][H][N][HD] | Vt [BM][H][HD][N]

typedef short s16x8 __attribute__((ext_vector_type(8)));
typedef unsigned short u16x8 __attribute__((ext_vector_type(8)));
typedef float f32x4 __attribute__((ext_vector_type(4)));

#define MFMA16(a, b, c) __builtin_amdgcn_mfma_f32_16x16x32_bf16((a), (b), (c), 0, 0, 0)

static __device__ __forceinline__ unsigned short f2bf(float f) {
    union { float f; unsigned u; } v; v.f = f;
    unsigned r = v.u + 0x7FFFu + ((v.u >> 16) & 1u);   // RNE
    return (unsigned short)(r >> 16);
}
// HW packed f32->bf16 RNE: lo = a, hi = b. No builtin on gfx950 -> inline asm.
static __device__ __forceinline__ unsigned pk2(float a, float b) {
    unsigned r;
    asm("v_cvt_pk_bf16_f32 %0, %1, %2" : "=v"(r) : "v"(a), "v"(b));
    return r;
}
// raw v_exp_f32 (2^x); args bounded ~[-2,2] here, no denorm/overflow concerns
static __device__ __forceinline__ float exp2_hw(float x) {
    float r;
    asm("v_exp_f32 %0, %1" : "=v"(r) : "v"(x));
    return r;
}

// ---------------------------------------------------------------------------
// Phase 1: QKV projection. 128x128 tile/block, 4 waves 2x2 of 64x64, BK=64.
// Round-1 structure (proven ~155us): single prefetch register set (ra/rb),
// double-buffered XOR-swizzled LDS, cvt_pk packed conversion. The Round-2
// 1.5-deep variant (4 register sets) spilled to scratch (WRITE_SIZE 441MB,
// 311us) -- +64 VGPR was NOT free. Do not re-add without checking numRegs.
// ---------------------------------------------------------------------------
#define OSTR 72

__global__ __launch_bounds__(256, 2)
void qkv_proj_kernel(const float* __restrict__ Xq, const float* __restrict__ Xk,
                     const float* __restrict__ Xv,
                     const float* __restrict__ Wq, const float* __restrict__ bq,
                     const float* __restrict__ Wk, const float* __restrict__ bk,
                     const float* __restrict__ Wv, const float* __restrict__ bv,
                     unsigned short* __restrict__ ws_q,
                     unsigned short* __restrict__ ws_k,
                     unsigned short* __restrict__ ws_vt)
{
    // byte layout: buf0 A [0,16K) B [16K,32K) | buf1 A [32K,48K) B [48K,64K)
    __shared__ __align__(16) char smem[65536];

    const int which = blockIdx.z;
    const float* X    = (which == 0) ? Xq : (which == 1) ? Xk : Xv;
    const float* W    = (which == 0) ? Wq : (which == 1) ? Wk : Wv;
    const float* bias = (which == 0) ? bq : (which == 1) ? bk : bv;

    const int r0 = blockIdx.x * 128;
    const int c0 = blockIdx.y * 128;
    const int tid = threadIdx.x;
    const int lane = tid & 63, wave = tid >> 6;
    const int l15 = lane & 15, quad = lane >> 4;
    const int wr = (wave >> 1) * 64, wc = (wave & 1) * 64;

    // staging roles: thread covers 16B granule scol of rows srow+16*i
    const int srow = tid >> 4;          // 0..15
    const int scol = tid & 15;          // 16B granule within 64-float k-slice
    const int cf = scol * 4;            // float col offset
    const int cb = scol * 8;            // byte col offset in 128B bf16 row

    f32x4 acc[4][4] = {};

    // prologue: stage k0=0 into buf0
    {
        char* A0 = smem;
        char* B0 = smem + 16384;
        for (int i = 0; i < 8; ++i) {
            const int row = i * 16 + srow;
            float4 fa = *(const float4*)&X[(size_t)(r0 + row) * 512 + cf];
            float4 fb = *(const float4*)&W[(size_t)(c0 + row) * 512 + cf];
            uint2 wa, wb;
            wa.x = pk2(fa.x, fa.y); wa.y = pk2(fa.z, fa.w);
            wb.x = pk2(fb.x, fb.y); wb.y = pk2(fb.z, fb.w);
            const int sw = cb ^ ((row & 7) << 4);
            *(uint2*)(A0 + row * 128 + sw) = wa;
            *(uint2*)(B0 + row * 128 + sw) = wb;
        }
    }
    __syncthreads();

    for (int it = 0; it < 8; ++it) {
        char* Ac = smem + (it & 1) * 32768;
        char* Bc = Ac + 16384;
        const bool pre = (it < 7);

        // issue next K-step's global loads early (land during MFMA below)
        float4 ra[8], rb[8];
        if (pre) {
            const int kn = (it + 1) * 64;
            for (int i = 0; i < 8; ++i) {
                const int row = i * 16 + srow;
                ra[i] = *(const float4*)&X[(size_t)(r0 + row) * 512 + kn + cf];
                rb[i] = *(const float4*)&W[(size_t)(c0 + row) * 512 + kn + cf];
            }
        }

        // MFMA on current buffer
        for (int kk = 0; kk < 2; ++kk) {
            s16x8 af[4], bf_[4];
            for (int mi = 0; mi < 4; ++mi) {
                const int row = wr + mi * 16 + l15;
                af[mi] = *(const s16x8*)(Ac + row * 128 +
                                         ((kk * 64 + quad * 16) ^ ((row & 7) << 4)));
            }
            for (int ni = 0; ni < 4; ++ni) {
                const int row = wc + ni * 16 + l15;
                bf_[ni] = *(const s16x8*)(Bc + row * 128 +
                                          ((kk * 64 + quad * 16) ^ ((row & 7) << 4)));
            }
            for (int mi = 0; mi < 4; ++mi)
                for (int ni = 0; ni < 4; ++ni)
                    acc[mi][ni] = MFMA16(af[mi], bf_[ni], acc[mi][ni]);
        }

        // convert + write prefetched tile to the other buffer
        if (pre) {
            char* An = smem + ((it & 1) ^ 1) * 32768;
            char* Bn = An + 16384;
            for (int i = 0; i < 8; ++i) {
                const int row = i * 16 + srow;
                uint2 wa, wb;
                wa.x = pk2(ra[i].x, ra[i].y); wa.y = pk2(ra[i].z, ra[i].w);
                wb.x = pk2(rb[i].x, rb[i].y); wb.y = pk2(rb[i].z, rb[i].w);
                const int sw = cb ^ ((row & 7) << 4);
                *(uint2*)(An + row * 128 + sw) = wa;
                *(uint2*)(Bn + row * 128 + sw) = wb;
            }
        }
        __syncthreads();
    }

    float bvals[4];
    for (int ni = 0; ni < 4; ++ni) bvals[ni] = bias[c0 + wc + ni * 16 + l15];

    __syncthreads();
    unsigned short* St = (unsigned short*)smem + wave * (64 * OSTR);
    const int h = blockIdx.y;
    const int bm = (r0 + wr) >> 11;
    const int n0 = (r0 + wr) & 2047;

    if (which != 2) {
        for (int mi = 0; mi < 4; ++mi)
            for (int ni = 0; ni < 4; ++ni)
                for (int r = 0; r < 4; ++r)
                    St[(mi * 16 + quad * 4 + r) * OSTR + ni * 16 + l15] =
                        f2bf(acc[mi][ni][r] + bvals[ni]);
        unsigned short* dst = (which == 0) ? ws_q : ws_k;
        for (int p = 0; p < 8; ++p) {
            const int row = p * 8 + (lane >> 3);
            const int coff = (lane & 7) * 8;
            s16x8 v = *(const s16x8*)&St[row * OSTR + coff];
            *(s16x8*)&dst[((size_t)(bm * 4 + h) * 2048 + n0 + row) * 128 + wc + coff] = v;
        }
    } else {
        for (int mi = 0; mi < 4; ++mi)
            for (int ni = 0; ni < 4; ++ni)
                for (int r = 0; r < 4; ++r)
                    St[(ni * 16 + l15) * OSTR + mi * 16 + quad * 4 + r] =
                        f2bf(acc[mi][ni][r] + bvals[ni]);
        for (int p = 0; p < 8; ++p) {
            const int col = p * 8 + (lane >> 3);
            const int roff = (lane & 7) * 8;
            s16x8 v = *(const s16x8*)&St[col * OSTR + roff];
            *(s16x8*)&ws_vt[(((size_t)(bm * 4 + h)) * 128 + wc + col) * 2048 + n0 + roff] = v;
        }
    }
}

// ---------------------------------------------------------------------------
// Phase 2: flash attention, Round 4: ZERO-LDS / ZERO-BARRIER streaming form.
//   Observation: all 4 waves of a block read IDENTICAL K/V fragments, the
//   per-iter K/V footprint is 16KB (fits L1), per-(bm,h) K+V is 1MB (fits L2
//   with XCD grouping), total K/V 48MB (fits L3). The LDS staging + per-iter
//   __syncthreads existed only to share data the caches already share; the
//   barrier serialized every iteration (~6400 cyc wall vs ~500 cyc of issue
//   work -- lesson #7: don't stage what caches fit). Now each wave is an
//   independent stream: fragments load straight from global (16x64B segments
//   per instruction, coalesced); latency hides under TLP (3 waves/SIMD) +
//   16-deep per-iter load batch. XCD swizzle co-locates the 16 q-blocks of
//   each (bm,h) on one XCD (~6MB/XCD working set, L2-mostly-resident).
//   __launch_bounds__(256,3) caps VGPR at 170 (demand ~155; R2 spill lesson:
//   verify no scratch via WRITE_SIZE).
// ---------------------------------------------------------------------------
__global__ __launch_bounds__(256, 3)
void attn_kernel(const unsigned short* __restrict__ Qw,
                 const unsigned short* __restrict__ Kw,
                 const unsigned short* __restrict__ Vtw,
                 float* __restrict__ out)
{
    const int tid = threadIdx.x, lane = tid & 63, wave = tid >> 6;
    const int l15 = lane & 15, quad = lane >> 4;

    // XCD-aware swizzle: linear id -> (xcd, idx); 16 q-tiles of one (bm,h)
    // stay on one XCD (assumes round-robin wg->XCD; wrong mapping only costs
    // locality, never correctness). 96 blocks/XCD = 6 combos x 16 q-tiles.
    const int lin = blockIdx.x + 16 * (blockIdx.y + 4 * blockIdx.z);
    const int xcd = lin & 7, ix = lin >> 3;        // ix in [0,96)
    const int combo = xcd * 6 + (ix >> 4);         // [0,48)
    const int qt = ix & 15;
    const int h = combo & 3, bm = combo >> 2;
    const int q0 = qt * 128;

    const unsigned short* Qh = Qw  + (size_t)(bm * 4 + h) * 2048 * 128;
    const unsigned short* Kh = Kw  + (size_t)(bm * 4 + h) * 2048 * 128;
    const unsigned short* Vh = Vtw + (size_t)(bm * 4 + h) * 128 * 2048;

    // qf: B-operand frags, 2 q-halves (qrow = q0 + wave*32 + qh*16 + l15)
    s16x8 qf[2][4];
    for (int qh = 0; qh < 2; ++qh)
        for (int kk = 0; kk < 4; ++kk)
            qf[qh][kk] = *(const s16x8*)&Qh[(size_t)(q0 + wave * 32 + qh * 16 + l15) * 128 + kk * 32 + quad * 8];

    f32x4 acc[2][8] = {};          // O^T: hd = mb*16+quad*4+r, qrow col = l15
    float rsum[2] = {0.f, 0.f};

    const float CEXP = 1.4426950408889634f / 11.313708498984761f;  // log2(e)/sqrt(128)

    for (int it = 0; it < 64; ++it) {
        const int k0 = it * 32;

        // ---- S^T = K Q^T, K fragments direct from global (L1/L2-hit) ----
        // kf0: rows k0..k0+15, kf1: rows k0+16..k0+31; 16B chunk per lane.
        f32x4 s[2][2] = {};
        __builtin_amdgcn_s_setprio(1);
        for (int kk = 0; kk < 4; ++kk) {
            s16x8 kf0 = *(const s16x8*)&Kh[(size_t)(k0 + l15) * 128 + kk * 32 + quad * 8];
            s16x8 kf1 = *(const s16x8*)&Kh[(size_t)(k0 + 16 + l15) * 128 + kk * 32 + quad * 8];
            s[0][0] = MFMA16(kf0, qf[0][kk], s[0][0]);
            s[0][1] = MFMA16(kf1, qf[0][kk], s[0][1]);
            s[1][0] = MFMA16(kf0, qf[1][kk], s[1][0]);
            s[1][1] = MFMA16(kf1, qf[1][kk], s[1][1]);
        }
        __builtin_amdgcn_s_setprio(0);

        // ---- P = exp2(S*CEXP); in-register quad exchange -> pf frags ----
        // swap32 then swap16 on (x0,x1) yields pf words 0 and 2; (y0,y1) -> 1,3.
        s16x8 pf[2];
        for (int qh = 0; qh < 2; ++qh) {
            const float p00 = exp2_hw(s[qh][0][0] * CEXP);
            const float p01 = exp2_hw(s[qh][0][1] * CEXP);
            const float p02 = exp2_hw(s[qh][0][2] * CEXP);
            const float p03 = exp2_hw(s[qh][0][3] * CEXP);
            const float p10 = exp2_hw(s[qh][1][0] * CEXP);
            const float p11 = exp2_hw(s[qh][1][1] * CEXP);
            const float p12 = exp2_hw(s[qh][1][2] * CEXP);
            const float p13 = exp2_hw(s[qh][1][3] * CEXP);
            rsum[qh] += ((p00 + p01) + (p02 + p03)) + ((p10 + p11) + (p12 + p13));
            unsigned x0 = pk2(p00, p01), y0 = pk2(p02, p03);
            unsigned x1 = pk2(p10, p11), y1 = pk2(p12, p13);
            asm("v_permlane32_swap_b32 %0, %1" : "+v"(x0), "+v"(x1));
            asm("v_permlane16_swap_b32 %0, %1" : "+v"(x0), "+v"(x1));
            asm("v_permlane32_swap_b32 %0, %1" : "+v"(y0), "+v"(y1));
            asm("v_permlane16_swap_b32 %0, %1" : "+v"(y0), "+v"(y1));
            union { unsigned u[4]; s16x8 v; } pu;
            pu.u[0] = x0; pu.u[1] = y0; pu.u[2] = x1; pu.u[3] = y1;
            pf[qh] = pu.v;
        }

        // ---- O^T += Vt P^T, V fragments direct from global ----
        __builtin_amdgcn_s_setprio(1);
        for (int mb = 0; mb < 8; ++mb) {
            s16x8 vtf = *(const s16x8*)&Vh[(size_t)(mb * 16 + l15) * 2048 + k0 + quad * 8];
            acc[0][mb] = MFMA16(vtf, pf[0], acc[0][mb]);
            acc[1][mb] = MFMA16(vtf, pf[1], acc[1][mb]);
        }
        __builtin_amdgcn_s_setprio(0);
    }

    // ---- epilogue: reduce rsum over quads, scale, direct float4 stores ----
    for (int qh = 0; qh < 2; ++qh) {
        rsum[qh] += __shfl_xor(rsum[qh], 16);
        rsum[qh] += __shfl_xor(rsum[qh], 32);
    }
    for (int qh = 0; qh < 2; ++qh) {
        const float inv = 1.f / rsum[qh];
        float* orow = out + ((size_t)bm * 2048 + q0 + wave * 32 + qh * 16 + l15) * 512 + h * 128;
        for (int mb = 0; mb < 8; ++mb) {
            float4 v;
            v.x = acc[qh][mb][0] * inv; v.y = acc[qh][mb][1] * inv;
            v.z = acc[qh][mb][2] * inv; v.w = acc[qh][mb][3] * inv;
            *(float4*)&orow[mb * 16 + quad * 4] = v;
        }
    }
}

extern "C" void kernel_launch(void* const* d_in, const int* in_sizes, int n_in,
                              void* d_out, int out_size, void* d_ws, size_t ws_size,
                              hipStream_t stream) {
    const float* Xq = (const float*)d_in[0];
    const float* Xk = (const float*)d_in[1];
    const float* Xv = (const float*)d_in[2];
    const float* Wq = (const float*)d_in[3];
    const float* bq = (const float*)d_in[4];
    const float* Wk = (const float*)d_in[5];
    const float* bk = (const float*)d_in[6];
    const float* Wv = (const float*)d_in[7];
    const float* bv = (const float*)d_in[8];
    float* out = (float*)d_out;

    unsigned short* ws = (unsigned short*)d_ws;
    const size_t per_tensor = (size_t)12 * 4 * 2048 * 128;
    unsigned short* ws_q  = ws;
    unsigned short* ws_k  = ws + per_tensor;
    unsigned short* ws_vt = ws + 2 * per_tensor;

    qkv_proj_kernel<<<dim3(192, 4, 3), 256, 0, stream>>>(
        Xq, Xk, Xv, Wq, bq, Wk, bk, Wv, bv, ws_q, ws_k, ws_vt);

    attn_kernel<<<dim3(16, 4, 12), 256, 0, stream>>>(ws_q, ws_k, ws_vt, out);
}

// Round 5
// 417.940 us; speedup vs baseline: 1.4691x; 1.4691x over previous
//
#include <hip/hip_runtime.h>
#include <hip/hip_bf16.h>

// B=4, M=3, N=2048, DIM=512, H=4, HD=128, SCALE=sqrt(128). BM=12.
// ws (bf16): Q [BM][H][N][HD] (PRE-SCALED by log2(e)/sqrt(128)) |
//            K [BM][H][N][HD] | Vt [BM][H][HD][N]

typedef short s16x8 __attribute__((ext_vector_type(8)));
typedef unsigned short u16x8 __attribute__((ext_vector_type(8)));
typedef float f32x4 __attribute__((ext_vector_type(4)));

#define MFMA16(a, b, c) __builtin_amdgcn_mfma_f32_16x16x32_bf16((a), (b), (c), 0, 0, 0)

static __device__ __forceinline__ unsigned short f2bf(float f) {
    union { float f; unsigned u; } v; v.f = f;
    unsigned r = v.u + 0x7FFFu + ((v.u >> 16) & 1u);   // RNE
    return (unsigned short)(r >> 16);
}
// HW packed f32->bf16 RNE: lo = a, hi = b. No builtin on gfx950 -> inline asm.
static __device__ __forceinline__ unsigned pk2(float a, float b) {
    unsigned r;
    asm("v_cvt_pk_bf16_f32 %0, %1, %2" : "=v"(r) : "v"(a), "v"(b));
    return r;
}
// raw v_exp_f32 (2^x); args bounded ~[-2,2] here, no denorm/overflow concerns
static __device__ __forceinline__ float exp2_hw(float x) {
    float r;
    asm("v_exp_f32 %0, %1" : "=v"(r) : "v"(x));
    return r;
}

// log2(e)/sqrt(128): folded into Q at projection time (round 5) so the attn
// inner loop does exp2(S) with zero pre-multiply.
#define CEXP_F 0.12755102905911087f

// ---------------------------------------------------------------------------
// Phase 1: QKV projection. 128x128 tile/block, 4 waves 2x2 of 64x64, BK=64.
// Round-1 structure (proven ~150us): single prefetch register set (ra/rb),
// double-buffered XOR-swizzled LDS, cvt_pk packed conversion. The Round-2
// 1.5-deep variant (4 register sets) spilled to scratch (WRITE_SIZE 441MB,
// 311us) -- +64 VGPR was NOT free. Do not re-add without checking numRegs.
// Round 5: Q output (which==0) scaled by CEXP_F before bf16 store.
// ---------------------------------------------------------------------------
#define OSTR 72

__global__ __launch_bounds__(256, 2)
void qkv_proj_kernel(const float* __restrict__ Xq, const float* __restrict__ Xk,
                     const float* __restrict__ Xv,
                     const float* __restrict__ Wq, const float* __restrict__ bq,
                     const float* __restrict__ Wk, const float* __restrict__ bk,
                     const float* __restrict__ Wv, const float* __restrict__ bv,
                     unsigned short* __restrict__ ws_q,
                     unsigned short* __restrict__ ws_k,
                     unsigned short* __restrict__ ws_vt)
{
    // byte layout: buf0 A [0,16K) B [16K,32K) | buf1 A [32K,48K) B [48K,64K)
    __shared__ __align__(16) char smem[65536];

    const int which = blockIdx.z;
    const float* X    = (which == 0) ? Xq : (which == 1) ? Xk : Xv;
    const float* W    = (which == 0) ? Wq : (which == 1) ? Wk : Wv;
    const float* bias = (which == 0) ? bq : (which == 1) ? bk : bv;

    const int r0 = blockIdx.x * 128;
    const int c0 = blockIdx.y * 128;
    const int tid = threadIdx.x;
    const int lane = tid & 63, wave = tid >> 6;
    const int l15 = lane & 15, quad = lane >> 4;
    const int wr = (wave >> 1) * 64, wc = (wave & 1) * 64;

    // staging roles: thread covers 16B granule scol of rows srow+16*i
    const int srow = tid >> 4;          // 0..15
    const int scol = tid & 15;          // 16B granule within 64-float k-slice
    const int cf = scol * 4;            // float col offset
    const int cb = scol * 8;            // byte col offset in 128B bf16 row

    f32x4 acc[4][4] = {};

    // prologue: stage k0=0 into buf0
    {
        char* A0 = smem;
        char* B0 = smem + 16384;
        for (int i = 0; i < 8; ++i) {
            const int row = i * 16 + srow;
            float4 fa = *(const float4*)&X[(size_t)(r0 + row) * 512 + cf];
            float4 fb = *(const float4*)&W[(size_t)(c0 + row) * 512 + cf];
            uint2 wa, wb;
            wa.x = pk2(fa.x, fa.y); wa.y = pk2(fa.z, fa.w);
            wb.x = pk2(fb.x, fb.y); wb.y = pk2(fb.z, fb.w);
            const int sw = cb ^ ((row & 7) << 4);
            *(uint2*)(A0 + row * 128 + sw) = wa;
            *(uint2*)(B0 + row * 128 + sw) = wb;
        }
    }
    __syncthreads();

    for (int it = 0; it < 8; ++it) {
        char* Ac = smem + (it & 1) * 32768;
        char* Bc = Ac + 16384;
        const bool pre = (it < 7);

        // issue next K-step's global loads early (land during MFMA below)
        float4 ra[8], rb[8];
        if (pre) {
            const int kn = (it + 1) * 64;
            for (int i = 0; i < 8; ++i) {
                const int row = i * 16 + srow;
                ra[i] = *(const float4*)&X[(size_t)(r0 + row) * 512 + kn + cf];
                rb[i] = *(const float4*)&W[(size_t)(c0 + row) * 512 + kn + cf];
            }
        }

        // MFMA on current buffer
        for (int kk = 0; kk < 2; ++kk) {
            s16x8 af[4], bf_[4];
            for (int mi = 0; mi < 4; ++mi) {
                const int row = wr + mi * 16 + l15;
                af[mi] = *(const s16x8*)(Ac + row * 128 +
                                         ((kk * 64 + quad * 16) ^ ((row & 7) << 4)));
            }
            for (int ni = 0; ni < 4; ++ni) {
                const int row = wc + ni * 16 + l15;
                bf_[ni] = *(const s16x8*)(Bc + row * 128 +
                                          ((kk * 64 + quad * 16) ^ ((row & 7) << 4)));
            }
            for (int mi = 0; mi < 4; ++mi)
                for (int ni = 0; ni < 4; ++ni)
                    acc[mi][ni] = MFMA16(af[mi], bf_[ni], acc[mi][ni]);
        }

        // convert + write prefetched tile to the other buffer
        if (pre) {
            char* An = smem + ((it & 1) ^ 1) * 32768;
            char* Bn = An + 16384;
            for (int i = 0; i < 8; ++i) {
                const int row = i * 16 + srow;
                uint2 wa, wb;
                wa.x = pk2(ra[i].x, ra[i].y); wa.y = pk2(ra[i].z, ra[i].w);
                wb.x = pk2(rb[i].x, rb[i].y); wb.y = pk2(rb[i].z, rb[i].w);
                const int sw = cb ^ ((row & 7) << 4);
                *(uint2*)(An + row * 128 + sw) = wa;
                *(uint2*)(Bn + row * 128 + sw) = wb;
            }
        }
        __syncthreads();
    }

    float bvals[4];
    for (int ni = 0; ni < 4; ++ni) bvals[ni] = bias[c0 + wc + ni * 16 + l15];

    // Q gets the softmax log2-scale folded in (free here, saves 16 VALU/iter
    // in the attn hot loop). K/V unscaled.
    const float oscale = (which == 0) ? CEXP_F : 1.0f;

    __syncthreads();
    unsigned short* St = (unsigned short*)smem + wave * (64 * OSTR);
    const int h = blockIdx.y;
    const int bm = (r0 + wr) >> 11;
    const int n0 = (r0 + wr) & 2047;

    if (which != 2) {
        for (int mi = 0; mi < 4; ++mi)
            for (int ni = 0; ni < 4; ++ni)
                for (int r = 0; r < 4; ++r)
                    St[(mi * 16 + quad * 4 + r) * OSTR + ni * 16 + l15] =
                        f2bf((acc[mi][ni][r] + bvals[ni]) * oscale);
        unsigned short* dst = (which == 0) ? ws_q : ws_k;
        for (int p = 0; p < 8; ++p) {
            const int row = p * 8 + (lane >> 3);
            const int coff = (lane & 7) * 8;
            s16x8 v = *(const s16x8*)&St[row * OSTR + coff];
            *(s16x8*)&dst[((size_t)(bm * 4 + h) * 2048 + n0 + row) * 128 + wc + coff] = v;
        }
    } else {
        for (int mi = 0; mi < 4; ++mi)
            for (int ni = 0; ni < 4; ++ni)
                for (int r = 0; r < 4; ++r)
                    St[(ni * 16 + l15) * OSTR + mi * 16 + quad * 4 + r] =
                        f2bf(acc[mi][ni][r] + bvals[ni]);
        for (int p = 0; p < 8; ++p) {
            const int col = p * 8 + (lane >> 3);
            const int roff = (lane & 7) * 8;
            s16x8 v = *(const s16x8*)&St[col * OSTR + roff];
            *(s16x8*)&ws_vt[(((size_t)(bm * 4 + h)) * 128 + wc + col) * 2048 + n0 + roff] = v;
        }
    }
}

// ---------------------------------------------------------------------------
// Phase 2: flash attention. R3 LDS-staged structure RESTORED (R4's zero-LDS
// form put ~200-400cyc global latency on the serial MFMA chain + V's 4KB
// stride thrashed L1 sets: 171->367us. LDS staging buys LATENCY, not BW --
// keep it). Round 5 changes (attack VALUBusy=50%, the top pipe):
//  (a) S*CEXP multiply gone -- Q pre-scaled at projection (16 v_mul/iter).
//  (b) rsum via ones-row MFMA: D=ones(16x32)*pf gives every lane
//      sum_k P[l15,k] in O-layout; 2 MFMA/iter replaces 14 v_add/iter and
//      the epilogue shuffle reduction. rsum now sums bf16-P, consistent
//      with the PV numerator.
// ---------------------------------------------------------------------------
#define VSTR 80    // V' row stride bytes (128 rows x 64B data + 16 pad)
// LDS: K0[8192] K1[8192] V0[10240] V1[10240] = 36864 B

__global__ __launch_bounds__(256)
void attn_kernel(const unsigned short* __restrict__ Qw,
                 const unsigned short* __restrict__ Kw,
                 const unsigned short* __restrict__ Vtw,
                 float* __restrict__ out)
{
    __shared__ char lds[36864];
    char* Kb0 = lds;
    char* Kb1 = lds + 8192;
    char* Vb0 = lds + 16384;
    char* Vb1 = lds + 26624;

    const int tid = threadIdx.x, lane = tid & 63, wave = tid >> 6;
    const int l15 = lane & 15, quad = lane >> 4;
    const int q0 = blockIdx.x * 128, h = blockIdx.y, bm = blockIdx.z;

    const unsigned short* Qh = Qw  + (size_t)(bm * 4 + h) * 2048 * 128;
    const unsigned short* Kh = Kw  + (size_t)(bm * 4 + h) * 2048 * 128;
    const unsigned short* Vh = Vtw + (size_t)(bm * 4 + h) * 128 * 2048;

    // staging roles (all 256 threads): K tile 32key x 128hd, V tile 128hd x 32n
    const int sk_key  = tid >> 3, sk_c   = tid & 7;   // 2x16B granules of a 256B K row
    const int sv_hd   = tid >> 1, sv_hlf = tid & 1;   // 2x16B chunks of a 64B V row
    const int skx = sk_key & 7;                       // K write-side granule xor
    const int krx = (l15 & 7) << 4;                   // K read-side byte xor

    // qf: B-operand frags, 2 q-halves (qrow = q0 + wave*32 + qh*16 + l15)
    s16x8 qf[2][4];
    for (int qh = 0; qh < 2; ++qh)
        for (int kk = 0; kk < 4; ++kk)
            qf[qh][kk] = *(const s16x8*)&Qh[(size_t)(q0 + wave * 32 + qh * 16 + l15) * 128 + kk * 32 + quad * 8];

    // ones fragment (bf16 1.0 x8) for the rsum MFMA
    s16x8 onesf;
    for (int i = 0; i < 8; ++i) onesf[i] = (short)0x3F80;

    // prologue: stage tile 0
    {
        u16x8 ka = *(const u16x8*)&Kh[(size_t)sk_key * 128 + sk_c * 16];
        u16x8 kb = *(const u16x8*)&Kh[(size_t)sk_key * 128 + sk_c * 16 + 8];
        u16x8 va = *(const u16x8*)&Vh[(size_t)sv_hd * 2048 + sv_hlf * 16];
        u16x8 vb = *(const u16x8*)&Vh[(size_t)sv_hd * 2048 + sv_hlf * 16 + 8];
        *(u16x8*)(Kb0 + sk_key * 256 + (((sk_c * 2) ^ skx) << 4))     = ka;
        *(u16x8*)(Kb0 + sk_key * 256 + (((sk_c * 2 + 1) ^ skx) << 4)) = kb;
        *(u16x8*)(Vb0 + sv_hd * VSTR + sv_hlf * 32)      = va;
        *(u16x8*)(Vb0 + sv_hd * VSTR + sv_hlf * 32 + 16) = vb;
    }
    __syncthreads();

    f32x4 acc[2][8] = {};          // O^T: hd = mb*16+quad*4+r, qrow col = l15
    f32x4 accr[2] = {};            // rsum rows (all identical): col = l15

    for (int it = 0; it < 64; ++it) {
        const int k0 = it * 32;
        char* Kc = (it & 1) ? Kb1 : Kb0;
        char* Vc = (it & 1) ? Vb1 : Vb0;
        char* Kn = (it & 1) ? Kb0 : Kb1;
        char* Vn = (it & 1) ? Vb0 : Vb1;
        const bool do_stage = (it < 63);

        // issue next-tile global loads at iteration top (whole iter to land)
        u16x8 ka, kb, va, vb;
        if (do_stage) {
            const int kn0 = k0 + 32;
            ka = *(const u16x8*)&Kh[(size_t)(kn0 + sk_key) * 128 + sk_c * 16];
            kb = *(const u16x8*)&Kh[(size_t)(kn0 + sk_key) * 128 + sk_c * 16 + 8];
            va = *(const u16x8*)&Vh[(size_t)sv_hd * 2048 + kn0 + sv_hlf * 16];
            vb = *(const u16x8*)&Vh[(size_t)sv_hd * 2048 + kn0 + sv_hlf * 16 + 8];
        }

        // ---- S^T = K Q^T on current K buffer (swizzled granule reads) ----
        // Q pre-scaled: s is already in log2 units.
        f32x4 s[2][2] = {};
        __builtin_amdgcn_s_setprio(1);
        for (int kk = 0; kk < 4; ++kk) {
            s16x8 kf0 = *(const s16x8*)(Kc + l15 * 256        + (((kk * 4 + quad) << 4) ^ krx));
            s16x8 kf1 = *(const s16x8*)(Kc + (16 + l15) * 256 + (((kk * 4 + quad) << 4) ^ krx));
            s[0][0] = MFMA16(kf0, qf[0][kk], s[0][0]);
            s[0][1] = MFMA16(kf1, qf[0][kk], s[0][1]);
            s[1][0] = MFMA16(kf0, qf[1][kk], s[1][0]);
            s[1][1] = MFMA16(kf1, qf[1][kk], s[1][1]);
        }
        __builtin_amdgcn_s_setprio(0);

        // ---- P = exp2(S); in-register quad exchange -> pf frags ----
        // swap32 then swap16 on (x0,x1) yields pf words 0 and 2; (y0,y1) -> 1,3.
        s16x8 pf[2];
        for (int qh = 0; qh < 2; ++qh) {
            const float p00 = exp2_hw(s[qh][0][0]);
            const float p01 = exp2_hw(s[qh][0][1]);
            const float p02 = exp2_hw(s[qh][0][2]);
            const float p03 = exp2_hw(s[qh][0][3]);
            const float p10 = exp2_hw(s[qh][1][0]);
            const float p11 = exp2_hw(s[qh][1][1]);
            const float p12 = exp2_hw(s[qh][1][2]);
            const float p13 = exp2_hw(s[qh][1][3]);
            unsigned x0 = pk2(p00, p01), y0 = pk2(p02, p03);
            unsigned x1 = pk2(p10, p11), y1 = pk2(p12, p13);
            asm("v_permlane32_swap_b32 %0, %1" : "+v"(x0), "+v"(x1));
            asm("v_permlane16_swap_b32 %0, %1" : "+v"(x0), "+v"(x1));
            asm("v_permlane32_swap_b32 %0, %1" : "+v"(y0), "+v"(y1));
            asm("v_permlane16_swap_b32 %0, %1" : "+v"(y0), "+v"(y1));
            union { unsigned u[4]; s16x8 v; } pu;
            pu.u[0] = x0; pu.u[1] = y0; pu.u[2] = x1; pu.u[3] = y1;
            pf[qh] = pu.v;
        }

        // ---- O^T += Vt P^T; rsum row += ones P^T (same B-operand) ----
        __builtin_amdgcn_s_setprio(1);
        accr[0] = MFMA16(onesf, pf[0], accr[0]);
        accr[1] = MFMA16(onesf, pf[1], accr[1]);
        for (int mb = 0; mb < 8; ++mb) {
            s16x8 vtf = *(const s16x8*)(Vc + (mb * 16 + l15) * VSTR + quad * 16);
            acc[0][mb] = MFMA16(vtf, pf[0], acc[0][mb]);
            acc[1][mb] = MFMA16(vtf, pf[1], acc[1][mb]);
        }
        __builtin_amdgcn_s_setprio(0);

        // ---- write staged next tile to LDS (post-PV: loads fully landed) ----
        if (do_stage) {
            *(u16x8*)(Kn + sk_key * 256 + (((sk_c * 2) ^ skx) << 4))     = ka;
            *(u16x8*)(Kn + sk_key * 256 + (((sk_c * 2 + 1) ^ skx) << 4)) = kb;
            *(u16x8*)(Vn + sv_hd * VSTR + sv_hlf * 32)      = va;
            *(u16x8*)(Vn + sv_hd * VSTR + sv_hlf * 32 + 16) = vb;
        }

        __syncthreads();   // staged buffer complete + current buffer reads done
    }

    // ---- epilogue: rsum already per-lane (col=l15); scale + float4 stores ----
    for (int qh = 0; qh < 2; ++qh) {
        const float inv = 1.f / accr[qh][0];
        float* orow = out + ((size_t)bm * 2048 + q0 + wave * 32 + qh * 16 + l15) * 512 + h * 128;
        for (int mb = 0; mb < 8; ++mb) {
            float4 v;
            v.x = acc[qh][mb][0] * inv; v.y = acc[qh][mb][1] * inv;
            v.z = acc[qh][mb][2] * inv; v.w = acc[qh][mb][3] * inv;
            *(float4*)&orow[mb * 16 + quad * 4] = v;
        }
    }
}

extern "C" void kernel_launch(void* const* d_in, const int* in_sizes, int n_in,
                              void* d_out, int out_size, void* d_ws, size_t ws_size,
                              hipStream_t stream) {
    const float* Xq = (const float*)d_in[0];
    const float* Xk = (const float*)d_in[1];
    const float* Xv = (const float*)d_in[2];
    const float* Wq = (const float*)d_in[3];
    const float* bq = (const float*)d_in[4];
    const float* Wk = (const float*)d_in[5];
    const float* bk = (const float*)d_in[6];
    const float* Wv = (const float*)d_in[7];
    const float* bv = (const float*)d_in[8];
    float* out = (float*)d_out;

    unsigned short* ws = (unsigned short*)d_ws;
    const size_t per_tensor = (size_t)12 * 4 * 2048 * 128;
    unsigned short* ws_q  = ws;
    unsigned short* ws_k  = ws + per_tensor;
    unsigned short* ws_vt = ws + 2 * per_tensor;

    qkv_proj_kernel<<<dim3(192, 4, 3), 256, 0, stream>>>(
        Xq, Xk, Xv, Wq, bq, Wk, bk, Wv, bv, ws_q, ws_k, ws_vt);

    attn_kernel<<<dim3(16, 4, 12), 256, 0, stream>>>(ws_q, ws_k, ws_vt, out);
}

// Round 6
// 385.295 us; speedup vs baseline: 1.5936x; 1.0847x over previous
//
#include <hip/hip_runtime.h>
#include <hip/hip_bf16.h>

// B=4, M=3, N=2048, DIM=512, H=4, HD=128, SCALE=sqrt(128). BM=12.
// ws (bf16): Q [BM][H][N][HD] (PRE-SCALED by log2(e)/sqrt(128)) |
//            K [BM][H][N][HD] | Vt [BM][H][HD][N]

typedef short s16x8 __attribute__((ext_vector_type(8)));
typedef unsigned short u16x8 __attribute__((ext_vector_type(8)));
typedef float f32x4 __attribute__((ext_vector_type(4)));

typedef const __attribute__((address_space(1))) void* gptr_t;
typedef __attribute__((address_space(3))) void* lptr_t;

#define MFMA16(a, b, c) __builtin_amdgcn_mfma_f32_16x16x32_bf16((a), (b), (c), 0, 0, 0)

static __device__ __forceinline__ unsigned short f2bf(float f) {
    union { float f; unsigned u; } v; v.f = f;
    unsigned r = v.u + 0x7FFFu + ((v.u >> 16) & 1u);   // RNE
    return (unsigned short)(r >> 16);
}
// HW packed f32->bf16 RNE: lo = a, hi = b. No builtin on gfx950 -> inline asm.
static __device__ __forceinline__ unsigned pk2(float a, float b) {
    unsigned r;
    asm("v_cvt_pk_bf16_f32 %0, %1, %2" : "=v"(r) : "v"(a), "v"(b));
    return r;
}
// raw v_exp_f32 (2^x); args bounded ~[-2,2] here, no denorm/overflow concerns
static __device__ __forceinline__ float exp2_hw(float x) {
    float r;
    asm("v_exp_f32 %0, %1" : "=v"(r) : "v"(x));
    return r;
}

// log2(e)/sqrt(128): folded into Q at projection time so the attn inner loop
// does exp2(S) with zero pre-multiply.
#define CEXP_F 0.12755102905911087f

// ---------------------------------------------------------------------------
// Phase 1: QKV projection, Round 6: global_load_lds staging.
// R1's register-prefetch pipeline was DEFEATED by the compiler (VGPR=72 proves
// the 64-VGPR prefetch set was never held across MFMA; the scheduler sank the
// vmcnt+convert+write to right after the loads -> serial HBM latency per iter,
// MfmaUtil 7%). Fix = m97 pattern: stage f32 tiles direct-to-LDS with
// __builtin_amdgcn_global_load_lds (no dest registers -> nothing to sink;
// loads stay in flight until the barrier drain). BK=32 so the f32 double
// buffer fits 64KB. XOR swizzle obtained by pre-swizzling the PER-LANE GLOBAL
// source address (m173); LDS dest stays linear (HW requires it). f32->bf16
// conversion moves into the fragment path (2x ds_read_b128 + 4 cvt_pk per
// fragment) -- same fragment values, same MFMA order as before: bit-identical.
// ---------------------------------------------------------------------------
#define OSTR 72

__global__ __launch_bounds__(256, 2)
void qkv_proj_kernel(const float* __restrict__ Xq, const float* __restrict__ Xk,
                     const float* __restrict__ Xv,
                     const float* __restrict__ Wq, const float* __restrict__ bq,
                     const float* __restrict__ Wk, const float* __restrict__ bk,
                     const float* __restrict__ Wv, const float* __restrict__ bv,
                     unsigned short* __restrict__ ws_q,
                     unsigned short* __restrict__ ws_k,
                     unsigned short* __restrict__ ws_vt)
{
    // byte layout: buf0 A [0,16K) B [16K,32K) | buf1 A [32K,48K) B [48K,64K)
    // each f32 tile: 128 rows x 32 f32 (128B row, 8x16B granules)
    __shared__ __align__(16) char smem[65536];

    const int which = blockIdx.z;
    const float* X    = (which == 0) ? Xq : (which == 1) ? Xk : Xv;
    const float* W    = (which == 0) ? Wq : (which == 1) ? Wk : Wv;
    const float* bias = (which == 0) ? bq : (which == 1) ? bk : bv;

    const int r0 = blockIdx.x * 128;
    const int c0 = blockIdx.y * 128;
    const int tid = threadIdx.x;
    const int lane = tid & 63, wave = tid >> 6;
    const int l15 = lane & 15, quad = lane >> 4;
    const int wr = (wave >> 1) * 64, wc = (wave & 1) * 64;

    // gload_lds lane roles: instr covers 8 rows x 128B; lane -> row base+(l>>3),
    // LDS granule l&7 (linear). Source granule XOR-swizzled: gg = (l&7)^((l>>3)&7).
    const int g_row = lane >> 3;                  // 0..7 within instr
    const int g_gg  = (lane & 7) ^ (g_row & 7);   // pre-swizzled source granule

    f32x4 acc[4][4] = {};

#define QKV_STAGE(BUF, IT) { \
        const int k0_ = (IT) * 32; \
        char* Ab_ = smem + (BUF) * 32768; \
        char* Bb_ = Ab_ + 16384; \
        _Pragma("unroll") \
        for (int jj = 0; jj < 4; ++jj) { \
            const int br_ = wave * 32 + jj * 8; \
            const int row_ = br_ + g_row; \
            const float* sa_ = &X[(size_t)(r0 + row_) * 512 + k0_ + g_gg * 4]; \
            const float* sb_ = &W[(size_t)(c0 + row_) * 512 + k0_ + g_gg * 4]; \
            __builtin_amdgcn_global_load_lds((gptr_t)(const void*)sa_, \
                (lptr_t)(void*)(Ab_ + br_ * 128), 16, 0, 0); \
            __builtin_amdgcn_global_load_lds((gptr_t)(const void*)sb_, \
                (lptr_t)(void*)(Bb_ + br_ * 128), 16, 0, 0); \
        } }

#define QKV_MFMA(BUF) { \
        char* Ac_ = smem + (BUF) * 32768; \
        char* Bc_ = Ac_ + 16384; \
        s16x8 af_[4], bf_[4]; \
        _Pragma("unroll") \
        for (int mi = 0; mi < 4; ++mi) { \
            const int row_ = wr + mi * 16 + l15; \
            const int x_ = row_ & 7; \
            f32x4 lo_ = *(const f32x4*)(Ac_ + row_ * 128 + (((2 * quad) ^ x_) << 4)); \
            f32x4 hi_ = *(const f32x4*)(Ac_ + row_ * 128 + (((2 * quad + 1) ^ x_) << 4)); \
            union { unsigned u[4]; s16x8 v; } p_; \
            p_.u[0] = pk2(lo_[0], lo_[1]); p_.u[1] = pk2(lo_[2], lo_[3]); \
            p_.u[2] = pk2(hi_[0], hi_[1]); p_.u[3] = pk2(hi_[2], hi_[3]); \
            af_[mi] = p_.v; \
        } \
        _Pragma("unroll") \
        for (int ni = 0; ni < 4; ++ni) { \
            const int row_ = wc + ni * 16 + l15; \
            const int x_ = row_ & 7; \
            f32x4 lo_ = *(const f32x4*)(Bc_ + row_ * 128 + (((2 * quad) ^ x_) << 4)); \
            f32x4 hi_ = *(const f32x4*)(Bc_ + row_ * 128 + (((2 * quad + 1) ^ x_) << 4)); \
            union { unsigned u[4]; s16x8 v; } p_; \
            p_.u[0] = pk2(lo_[0], lo_[1]); p_.u[1] = pk2(lo_[2], lo_[3]); \
            p_.u[2] = pk2(hi_[0], hi_[1]); p_.u[3] = pk2(hi_[2], hi_[3]); \
            bf_[ni] = p_.v; \
        } \
        _Pragma("unroll") \
        for (int mi = 0; mi < 4; ++mi) \
            _Pragma("unroll") \
            for (int ni = 0; ni < 4; ++ni) \
                acc[mi][ni] = MFMA16(af_[mi], bf_[ni], acc[mi][ni]); \
    }

    // prologue: stage k-slice 0 into buf0
    QKV_STAGE(0, 0);
    __syncthreads();

    for (int it = 0; it < 16; ++it) {
        const int cur = it & 1;
        if (it < 15) QKV_STAGE(cur ^ 1, it + 1);   // in flight across MFMA
        QKV_MFMA(cur);
        __syncthreads();   // drains vmcnt (staged tile) + read-done on cur
    }

#undef QKV_STAGE
#undef QKV_MFMA

    float bvals[4];
    for (int ni = 0; ni < 4; ++ni) bvals[ni] = bias[c0 + wc + ni * 16 + l15];

    // Q gets the softmax log2-scale folded in (saves 16 VALU/iter in attn).
    const float oscale = (which == 0) ? CEXP_F : 1.0f;

    __syncthreads();
    unsigned short* St = (unsigned short*)smem + wave * (64 * OSTR);
    const int h = blockIdx.y;
    const int bm = (r0 + wr) >> 11;
    const int n0 = (r0 + wr) & 2047;

    if (which != 2) {
        for (int mi = 0; mi < 4; ++mi)
            for (int ni = 0; ni < 4; ++ni)
                for (int r = 0; r < 4; ++r)
                    St[(mi * 16 + quad * 4 + r) * OSTR + ni * 16 + l15] =
                        f2bf((acc[mi][ni][r] + bvals[ni]) * oscale);
        unsigned short* dst = (which == 0) ? ws_q : ws_k;
        for (int p = 0; p < 8; ++p) {
            const int row = p * 8 + (lane >> 3);
            const int coff = (lane & 7) * 8;
            s16x8 v = *(const s16x8*)&St[row * OSTR + coff];
            *(s16x8*)&dst[((size_t)(bm * 4 + h) * 2048 + n0 + row) * 128 + wc + coff] = v;
        }
    } else {
        for (int mi = 0; mi < 4; ++mi)
            for (int ni = 0; ni < 4; ++ni)
                for (int r = 0; r < 4; ++r)
                    St[(ni * 16 + l15) * OSTR + mi * 16 + quad * 4 + r] =
                        f2bf(acc[mi][ni][r] + bvals[ni]);
        for (int p = 0; p < 8; ++p) {
            const int col = p * 8 + (lane >> 3);
            const int roff = (lane & 7) * 8;
            s16x8 v = *(const s16x8*)&St[col * OSTR + roff];
            *(s16x8*)&ws_vt[(((size_t)(bm * 4 + h)) * 128 + wc + col) * 2048 + n0 + roff] = v;
        }
    }
}

// ---------------------------------------------------------------------------
// Phase 2: flash attention. FROZEN at Round-5 form (167us, proven):
// R3 LDS-staged double-buffer structure (R4's zero-LDS regressed 171->367us:
// global latency on the serial MFMA chain), K granule-XOR swizzle both sides,
// P via permlane quad-exchange, Q pre-scaled, rsum via ones-row MFMA.
// ---------------------------------------------------------------------------
#define VSTR 80    // V' row stride bytes (128 rows x 64B data + 16 pad)
// LDS: K0[8192] K1[8192] V0[10240] V1[10240] = 36864 B

__global__ __launch_bounds__(256)
void attn_kernel(const unsigned short* __restrict__ Qw,
                 const unsigned short* __restrict__ Kw,
                 const unsigned short* __restrict__ Vtw,
                 float* __restrict__ out)
{
    __shared__ char lds[36864];
    char* Kb0 = lds;
    char* Kb1 = lds + 8192;
    char* Vb0 = lds + 16384;
    char* Vb1 = lds + 26624;

    const int tid = threadIdx.x, lane = tid & 63, wave = tid >> 6;
    const int l15 = lane & 15, quad = lane >> 4;
    const int q0 = blockIdx.x * 128, h = blockIdx.y, bm = blockIdx.z;

    const unsigned short* Qh = Qw  + (size_t)(bm * 4 + h) * 2048 * 128;
    const unsigned short* Kh = Kw  + (size_t)(bm * 4 + h) * 2048 * 128;
    const unsigned short* Vh = Vtw + (size_t)(bm * 4 + h) * 128 * 2048;

    // staging roles (all 256 threads): K tile 32key x 128hd, V tile 128hd x 32n
    const int sk_key  = tid >> 3, sk_c   = tid & 7;   // 2x16B granules of a 256B K row
    const int sv_hd   = tid >> 1, sv_hlf = tid & 1;   // 2x16B chunks of a 64B V row
    const int skx = sk_key & 7;                       // K write-side granule xor
    const int krx = (l15 & 7) << 4;                   // K read-side byte xor

    // qf: B-operand frags, 2 q-halves (qrow = q0 + wave*32 + qh*16 + l15)
    s16x8 qf[2][4];
    for (int qh = 0; qh < 2; ++qh)
        for (int kk = 0; kk < 4; ++kk)
            qf[qh][kk] = *(const s16x8*)&Qh[(size_t)(q0 + wave * 32 + qh * 16 + l15) * 128 + kk * 32 + quad * 8];

    // ones fragment (bf16 1.0 x8) for the rsum MFMA
    s16x8 onesf;
    for (int i = 0; i < 8; ++i) onesf[i] = (short)0x3F80;

    // prologue: stage tile 0
    {
        u16x8 ka = *(const u16x8*)&Kh[(size_t)sk_key * 128 + sk_c * 16];
        u16x8 kb = *(const u16x8*)&Kh[(size_t)sk_key * 128 + sk_c * 16 + 8];
        u16x8 va = *(const u16x8*)&Vh[(size_t)sv_hd * 2048 + sv_hlf * 16];
        u16x8 vb = *(const u16x8*)&Vh[(size_t)sv_hd * 2048 + sv_hlf * 16 + 8];
        *(u16x8*)(Kb0 + sk_key * 256 + (((sk_c * 2) ^ skx) << 4))     = ka;
        *(u16x8*)(Kb0 + sk_key * 256 + (((sk_c * 2 + 1) ^ skx) << 4)) = kb;
        *(u16x8*)(Vb0 + sv_hd * VSTR + sv_hlf * 32)      = va;
        *(u16x8*)(Vb0 + sv_hd * VSTR + sv_hlf * 32 + 16) = vb;
    }
    __syncthreads();

    f32x4 acc[2][8] = {};          // O^T: hd = mb*16+quad*4+r, qrow col = l15
    f32x4 accr[2] = {};            // rsum rows (all identical): col = l15

    for (int it = 0; it < 64; ++it) {
        const int k0 = it * 32;
        char* Kc = (it & 1) ? Kb1 : Kb0;
        char* Vc = (it & 1) ? Vb1 : Vb0;
        char* Kn = (it & 1) ? Kb0 : Kb1;
        char* Vn = (it & 1) ? Vb0 : Vb1;
        const bool do_stage = (it < 63);

        // issue next-tile global loads at iteration top (whole iter to land)
        u16x8 ka, kb, va, vb;
        if (do_stage) {
            const int kn0 = k0 + 32;
            ka = *(const u16x8*)&Kh[(size_t)(kn0 + sk_key) * 128 + sk_c * 16];
            kb = *(const u16x8*)&Kh[(size_t)(kn0 + sk_key) * 128 + sk_c * 16 + 8];
            va = *(const u16x8*)&Vh[(size_t)sv_hd * 2048 + kn0 + sv_hlf * 16];
            vb = *(const u16x8*)&Vh[(size_t)sv_hd * 2048 + kn0 + sv_hlf * 16 + 8];
        }

        // ---- S^T = K Q^T on current K buffer (swizzled granule reads) ----
        // Q pre-scaled: s is already in log2 units.
        f32x4 s[2][2] = {};
        __builtin_amdgcn_s_setprio(1);
        for (int kk = 0; kk < 4; ++kk) {
            s16x8 kf0 = *(const s16x8*)(Kc + l15 * 256        + (((kk * 4 + quad) << 4) ^ krx));
            s16x8 kf1 = *(const s16x8*)(Kc + (16 + l15) * 256 + (((kk * 4 + quad) << 4) ^ krx));
            s[0][0] = MFMA16(kf0, qf[0][kk], s[0][0]);
            s[0][1] = MFMA16(kf1, qf[0][kk], s[0][1]);
            s[1][0] = MFMA16(kf0, qf[1][kk], s[1][0]);
            s[1][1] = MFMA16(kf1, qf[1][kk], s[1][1]);
        }
        __builtin_amdgcn_s_setprio(0);

        // ---- P = exp2(S); in-register quad exchange -> pf frags ----
        s16x8 pf[2];
        for (int qh = 0; qh < 2; ++qh) {
            const float p00 = exp2_hw(s[qh][0][0]);
            const float p01 = exp2_hw(s[qh][0][1]);
            const float p02 = exp2_hw(s[qh][0][2]);
            const float p03 = exp2_hw(s[qh][0][3]);
            const float p10 = exp2_hw(s[qh][1][0]);
            const float p11 = exp2_hw(s[qh][1][1]);
            const float p12 = exp2_hw(s[qh][1][2]);
            const float p13 = exp2_hw(s[qh][1][3]);
            unsigned x0 = pk2(p00, p01), y0 = pk2(p02, p03);
            unsigned x1 = pk2(p10, p11), y1 = pk2(p12, p13);
            asm("v_permlane32_swap_b32 %0, %1" : "+v"(x0), "+v"(x1));
            asm("v_permlane16_swap_b32 %0, %1" : "+v"(x0), "+v"(x1));
            asm("v_permlane32_swap_b32 %0, %1" : "+v"(y0), "+v"(y1));
            asm("v_permlane16_swap_b32 %0, %1" : "+v"(y0), "+v"(y1));
            union { unsigned u[4]; s16x8 v; } pu;
            pu.u[0] = x0; pu.u[1] = y0; pu.u[2] = x1; pu.u[3] = y1;
            pf[qh] = pu.v;
        }

        // ---- O^T += Vt P^T; rsum row += ones P^T (same B-operand) ----
        __builtin_amdgcn_s_setprio(1);
        accr[0] = MFMA16(onesf, pf[0], accr[0]);
        accr[1] = MFMA16(onesf, pf[1], accr[1]);
        for (int mb = 0; mb < 8; ++mb) {
            s16x8 vtf = *(const s16x8*)(Vc + (mb * 16 + l15) * VSTR + quad * 16);
            acc[0][mb] = MFMA16(vtf, pf[0], acc[0][mb]);
            acc[1][mb] = MFMA16(vtf, pf[1], acc[1][mb]);
        }
        __builtin_amdgcn_s_setprio(0);

        // ---- write staged next tile to LDS (post-PV: loads fully landed) ----
        if (do_stage) {
            *(u16x8*)(Kn + sk_key * 256 + (((sk_c * 2) ^ skx) << 4))     = ka;
            *(u16x8*)(Kn + sk_key * 256 + (((sk_c * 2 + 1) ^ skx) << 4)) = kb;
            *(u16x8*)(Vn + sv_hd * VSTR + sv_hlf * 32)      = va;
            *(u16x8*)(Vn + sv_hd * VSTR + sv_hlf * 32 + 16) = vb;
        }

        __syncthreads();   // staged buffer complete + current buffer reads done
    }

    // ---- epilogue: rsum already per-lane (col=l15); scale + float4 stores ----
    for (int qh = 0; qh < 2; ++qh) {
        const float inv = 1.f / accr[qh][0];
        float* orow = out + ((size_t)bm * 2048 + q0 + wave * 32 + qh * 16 + l15) * 512 + h * 128;
        for (int mb = 0; mb < 8; ++mb) {
            float4 v;
            v.x = acc[qh][mb][0] * inv; v.y = acc[qh][mb][1] * inv;
            v.z = acc[qh][mb][2] * inv; v.w = acc[qh][mb][3] * inv;
            *(float4*)&orow[mb * 16 + quad * 4] = v;
        }
    }
}

extern "C" void kernel_launch(void* const* d_in, const int* in_sizes, int n_in,
                              void* d_out, int out_size, void* d_ws, size_t ws_size,
                              hipStream_t stream) {
    const float* Xq = (const float*)d_in[0];
    const float* Xk = (const float*)d_in[1];
    const float* Xv = (const float*)d_in[2];
    const float* Wq = (const float*)d_in[3];
    const float* bq = (const float*)d_in[4];
    const float* Wk = (const float*)d_in[5];
    const float* bk = (const float*)d_in[6];
    const float* Wv = (const float*)d_in[7];
    const float* bv = (const float*)d_in[8];
    float* out = (float*)d_out;

    unsigned short* ws = (unsigned short*)d_ws;
    const size_t per_tensor = (size_t)12 * 4 * 2048 * 128;
    unsigned short* ws_q  = ws;
    unsigned short* ws_k  = ws + per_tensor;
    unsigned short* ws_vt = ws + 2 * per_tensor;

    qkv_proj_kernel<<<dim3(192, 4, 3), 256, 0, stream>>>(
        Xq, Xk, Xv, Wq, bq, Wk, bk, Wv, bv, ws_q, ws_k, ws_vt);

    attn_kernel<<<dim3(16, 4, 12), 256, 0, stream>>>(ws_q, ws_k, ws_vt, out);
}